// Round 4
// baseline (55.606 us; speedup 1.0000x reference)
//
#include <hip/hip_runtime.h>
#include <math.h>

#define SZ 28

__constant__ int c_fy[10] = {4,4,4,14,14,14,24,24,24,12};
__constant__ int c_fx[10] = {4,14,24,4,14,24,4,14,24,12};

// ---------------------------------------------------------------------------
// Prep: collapse exp(i*phase)*ifft2(H) circular conv into packed bf16 weights.
// g = ifft2(H) = outer(g1,g1), g1 = ifft(h1), h1 = exp(-i*pi*m^2/196).
// Angle as exact rational multiple of 2*pi: (-m^2 + 14*k*t)/392 -> sincosf of
// arg <= 2*pi (float-accurate, no doubles).
// Virtual outputs v in [0,20): v<10 -> Re(out v), v>=10 -> Im(out v-10).
// Pack layout (dwords): w3[((c*28+j)*2+g)*20 + e*5 + i] =
//     bf16(W[g*10+2i]) | bf16(W[g*10+2i+1])<<16   for pixel (c,j,e).
// ---------------------------------------------------------------------------
__device__ static inline unsigned int f2bf(float v) {
    unsigned int u = __float_as_uint(v);
    return (u + 0x7fffu + ((u >> 16) & 1u)) >> 16;   // RNE
}

__global__ __launch_bounds__(784) void prep_weights(const float* __restrict__ phase,
                                                    unsigned int* __restrict__ w3) {
    __shared__ float tr[SZ][SZ], ti[SZ][SZ];
    __shared__ float g1r[SZ], g1i[SZ];
    const int tid = threadIdx.x;                    // 0..783
    {
        const int t = tid / SZ, k = tid % SZ;
        const int m = (k <= SZ / 2) ? k : SZ - k;
        int num = (14 * k * t - m * m) % 392; if (num < 0) num += 392;
        float s, c;
        sincosf((float)num * (6.283185307179586f / 392.0f), &s, &c);
        tr[t][k] = c; ti[t][k] = s;
    }
    __syncthreads();
    if (tid < SZ) {
        float ar = 0.f, ai = 0.f;
        for (int k = 0; k < SZ; ++k) { ar += tr[tid][k]; ai += ti[tid][k]; }
        g1r[tid] = ar / 28.f; g1i[tid] = ai / 28.f;
    }
    __syncthreads();
    float Wv[20];
    {
        const int y = tid / SZ, x = tid % SZ;
        float sp, cp; sincosf(phase[tid], &sp, &cp);
        #pragma unroll
        for (int p = 0; p < 10; ++p) {
            const int dy = (c_fy[p] - y + SZ) % SZ;
            const int dx = (c_fx[p] - x + SZ) % SZ;
            const float Gr = g1r[dy] * g1r[dx] - g1i[dy] * g1i[dx];
            const float Gi = g1r[dy] * g1i[dx] + g1i[dy] * g1r[dx];
            Wv[p]      = cp * Gr - sp * Gi;          // Re
            Wv[10 + p] = cp * Gi + sp * Gr;          // Im
        }
    }
    {
        const int f4 = tid >> 2, e = tid & 3;
        const int c = f4 / SZ, j = f4 % SZ;
        #pragma unroll
        for (int g = 0; g < 2; ++g)
            #pragma unroll
            for (int i = 0; i < 5; ++i) {
                const unsigned int d = f2bf(Wv[g*10 + 2*i])
                                     | (f2bf(Wv[g*10 + 2*i + 1]) << 16);
                w3[(((c*SZ + j)*2 + g)*20) + e*5 + i] = d;
            }
    }
}

// ---------------------------------------------------------------------------
// Main: block = 512 thr = 8 waves = (q in 0..3 K-quarter) x (g in 0..1 outputs
// 10g..10g+10), 64 rows per block. x staged f32 via global_load_lds into
// [64 rows][29 f4] (stride 464B: bank-group start cycles all 8 groups/8 rows).
// w: 20 bf16-dwords per (j) step, SGPR-rotated 3-deep, prefetched 2 steps
// ahead (crosses the chunk barrier -> scalar latency fully hidden); unpack is
// SALU shl/and (bf16->f32 == <<16).
// ---------------------------------------------------------------------------
__device__ static inline void gload_lds16(const float* src, char* lds_dst) {
    __builtin_amdgcn_global_load_lds(
        (const __attribute__((address_space(1))) void*)src,
        (__attribute__((address_space(3))) void*)lds_dst, 16, 0, 0);
}

__global__ __launch_bounds__(512) void focus_gemm(const float* __restrict__ x,
                                                  const unsigned int* __restrict__ w3,
                                                  float* __restrict__ out) {
    __shared__ char smem[59392];                   // 2 x 29696 stage; union red

    const int tid  = threadIdx.x;
    const int lane = tid & 63;
    const int w8 = __builtin_amdgcn_readfirstlane(tid >> 6);  // 0..7
    const int q = w8 & 3, g = w8 >> 1 >> 1 ? 0 : 0;           // placeholder
    const int gg = w8 >> 2;                                   // 0..1
    const int row0 = blockIdx.x * 64;

    float acc[10];
    #pragma unroll
    for (int k = 0; k < 10; ++k) acc[k] = 0.f;

    // stage chunk c into buffer b: linear slots s = i*64+lane, s -> (r,j):
    // r = s/29, j = s%29 (j==28 = pad, written never read)
    auto stage = [&](int b, int c) {
        char* buf = smem + b * 29696;
        for (int i = w8; i < 29; i += 8) {
            const unsigned int s = (unsigned)(i * 64 + lane);
            const unsigned int r = s / 29u;
            const unsigned int j = s - r * 29u;
            const float* src = (j < 28u)
                ? (x + ((size_t)(row0 + r) * 196 + c * 28 + j) * 4)
                : x;                                   // pad: dummy valid line
            gload_lds16(src, buf + (size_t)i * 1024);  // dest uniform+lane*16
        }
    };

    auto loadW = [&](unsigned int* d, int c, int jl) {
        const unsigned int* p = w3 + (size_t)(((c * 28 + q * 7 + jl) * 2 + gg) * 20);
        #pragma unroll
        for (int i = 0; i < 20; ++i) d[i] = p[i];
    };

    unsigned int wA[20], wB[20], wT[20];
    loadW(wA, 0, 0);                               // prefetch depth 2
    loadW(wB, 0, 1);
    stage(0, 0);

    for (int c = 0; c < 7; ++c) {
        __syncthreads();                           // publishes chunk c
        if (c < 6) stage((c & 1) ^ 1, c + 1);      // next chunk under compute
        const float4* buf = (const float4*)(smem + (c & 1) * 29696);
        #pragma unroll
        for (int jl = 0; jl < 7; ++jl) {
            const int pc = (jl < 5) ? c : ((c + 1 < 7) ? c + 1 : 0);
            const int pj = (jl < 5) ? jl + 2 : jl - 5;
            loadW(wT, pc, pj);                     // keep 2-deep pipeline
            const float4 xv = buf[(size_t)lane * 29 + q * 7 + jl];
            #pragma unroll
            for (int e = 0; e < 4; ++e) {
                const float xs = (&xv.x)[e];
                #pragma unroll
                for (int i = 0; i < 5; ++i) {
                    const unsigned int wd = wA[e * 5 + i];
                    acc[2*i]   = fmaf(xs, __uint_as_float(wd << 16),         acc[2*i]);
                    acc[2*i+1] = fmaf(xs, __uint_as_float(wd & 0xffff0000u), acc[2*i+1]);
                }
            }
            #pragma unroll
            for (int i = 0; i < 20; ++i) { wA[i] = wB[i]; wB[i] = wT[i]; }
        }
    }

    __syncthreads();                               // all buf reads done
    float* red = (float*)smem;                     // [2][4][64][11] = 22.5 KB
    #pragma unroll
    for (int k = 0; k < 10; ++k)
        red[((gg * 4 + q) * 64 + lane) * 11 + k] = acc[k];
    __syncthreads();

    if (tid < 64) {
        float sr[10], si[10];
        #pragma unroll
        for (int k = 0; k < 10; ++k) {
            float a = 0.f, b = 0.f;
            #pragma unroll
            for (int p = 0; p < 4; ++p) {
                a += red[((p) * 64 + tid) * 11 + k];
                b += red[((4 + p) * 64 + tid) * 11 + k];
            }
            sr[k] = a; si[k] = b;
        }
        float2* o2 = (float2*)(out + (size_t)(row0 + tid) * 10);
        #pragma unroll
        for (int p = 0; p < 5; ++p) {
            float2 v;
            v.x = sr[2*p]   * sr[2*p]   + si[2*p]   * si[2*p];
            v.y = sr[2*p+1] * sr[2*p+1] + si[2*p+1] * si[2*p+1];
            o2[p] = v;
        }
    }
    (void)q; (void)g;
}

extern "C" void kernel_launch(void* const* d_in, const int* in_sizes, int n_in,
                              void* d_out, int out_size, void* d_ws, size_t ws_size,
                              hipStream_t stream) {
    const float* x     = (const float*)d_in[0];   // [32768,1,28,28] f32
    const float* phase = (const float*)d_in[1];   // [28,28] f32
    float* out = (float*)d_out;                   // [32768,10] f32
    unsigned int* w3 = (unsigned int*)d_ws;       // 784*2*20 dwords = 122.5 KB

    hipLaunchKernelGGL(prep_weights, dim3(1), dim3(SZ * SZ), 0, stream, phase, w3);

    const int B = in_sizes[0] / (SZ * SZ);        // 32768
    hipLaunchKernelGGL(focus_gemm, dim3(B / 64), dim3(512), 0, stream, x, w3, out);
}

// Round 6
// 27.000 us; speedup vs baseline: 2.0595x; 2.0595x over previous
//
#include <hip/hip_runtime.h>
#include <math.h>

#define SZ 28

__constant__ int c_fy[10] = {4,4,4,14,14,14,24,24,24,12};
__constant__ int c_fx[10] = {4,14,24,4,14,24,4,14,24,12};

typedef __attribute__((ext_vector_type(4)))  float    f32x4;
typedef __attribute__((ext_vector_type(16))) float    f32x16;
typedef __attribute__((ext_vector_type(8)))  _Float16 f16x8;

// ---------------------------------------------------------------------------
// Prep: collapse exp(i*phase)*ifft2(H) circular conv into f16 MFMA B-fragments.
// g = ifft2(H) = outer(g1,g1), g1 = ifft(h1), h1 = exp(-i*pi*m^2/196).
// Virtual cols v: v=2p -> Re(out p), v=2p+1 -> Im(out p) (v<20), else 0.
// B-frag layout for mfma_f32_32x32x16_f16 (K=784 = 49 ksteps of 16):
//   lane l holds B[k = s*16 + (l>>5)*8 + j][col = l&31], j=0..7
//   w2[s*512 + ((b*32)+v)*8 + j],  b=(k>>3)&1  -> per kstep 1KB, lane-linear.
// ---------------------------------------------------------------------------
__global__ __launch_bounds__(784) void prep_weights(const float* __restrict__ phase,
                                                    _Float16* __restrict__ w2) {
    __shared__ float tr[SZ][SZ], ti[SZ][SZ];
    __shared__ float g1r[SZ], g1i[SZ];
    const int tid = threadIdx.x;                    // 0..783 = pixel k
    {
        const int t = tid / SZ, k = tid % SZ;
        const int m = (k <= SZ / 2) ? k : SZ - k;
        int num = (14 * k * t - m * m) % 392; if (num < 0) num += 392;
        float s, c;
        sincosf((float)num * (6.283185307179586f / 392.0f), &s, &c);
        tr[t][k] = c; ti[t][k] = s;
    }
    __syncthreads();
    if (tid < SZ) {
        float ar = 0.f, ai = 0.f;
        for (int k = 0; k < SZ; ++k) { ar += tr[tid][k]; ai += ti[tid][k]; }
        g1r[tid] = ar / 28.f; g1i[tid] = ai / 28.f;
    }
    __syncthreads();
    float Wv[20];
    {
        const int y = tid / SZ, x = tid % SZ;
        float sp, cp; sincosf(phase[tid], &sp, &cp);
        #pragma unroll
        for (int p = 0; p < 10; ++p) {
            const int dy = (c_fy[p] - y + SZ) % SZ;
            const int dx = (c_fx[p] - x + SZ) % SZ;
            const float Gr = g1r[dy] * g1r[dx] - g1i[dy] * g1i[dx];
            const float Gi = g1r[dy] * g1i[dx] + g1i[dy] * g1r[dx];
            Wv[p]      = cp * Gr - sp * Gi;          // Re
            Wv[10 + p] = cp * Gi + sp * Gr;          // Im
        }
    }
    {
        const int k = tid;
        const int s = k >> 4, b = (k >> 3) & 1, j = k & 7;
        #pragma unroll
        for (int v = 0; v < 32; ++v) {
            float val = 0.f;
            if (v < 20) val = (v & 1) ? Wv[10 + (v >> 1)] : Wv[v >> 1];
            w2[s * 512 + (b * 32 + v) * 8 + j] = (_Float16)val;
        }
    }
}

// ---------------------------------------------------------------------------
// Main MFMA GEMM: C[64 rows x 32 cols] per block = X-tile * W, then
// out[row][p] = C[row][2p]^2 + C[row][2p+1]^2 (adjacent-lane shfl_xor).
// Block = 256 thr = 4 waves: wave q -> mtile m=q>>1 (32 rows), K-parity p=q&1
// (p=0: ksteps 0-3 of chunk, p=1: 4-6). 7 chunks x 7 ksteps = 49.
// x: reg-staged f32->f16 (cvt_pkrtz) into fragment-order LDS, lane^s swizzle,
// double-buffered, loads issued 1 chunk ahead. W: global_load_lds (16B),
// lane-linear, double-buffered. acc pair-reduced via LDS at the end.
// LDS: bufA 2x14336 + bufB 2x7168 = 43008 B -> 3 blocks/CU.
// ---------------------------------------------------------------------------
__device__ static inline void gload_lds16(const void* src, char* lds_dst) {
    __builtin_amdgcn_global_load_lds(
        (const __attribute__((address_space(1))) void*)src,
        (__attribute__((address_space(3))) void*)lds_dst, 16, 0, 0);
}

__global__ __launch_bounds__(256, 3) void focus_gemm(const float* __restrict__ x,
                                                     const _Float16* __restrict__ w2,
                                                     float* __restrict__ out) {
    __shared__ char smem[43008];
    const int tid  = threadIdx.x;
    const int lane = tid & 63;
    const int q = __builtin_amdgcn_readfirstlane(tid >> 6);  // 0..3
    const int m = q >> 1;                                    // mtile
    const int p = q & 1;                                     // kstep half
    const int row0 = blockIdx.x * 64;

    f32x16 acc;
    #pragma unroll
    for (int i = 0; i < 16; ++i) acc[i] = 0.f;

    char* const bA0 = smem;                 // 2 x 14336
    char* const bB0 = smem + 28672;         // 2 x 7168

    // -- W staging: wave q loads ksteps s = q, q+4 of chunk c (1KB each) --
    auto stageB = [&](int c) {
        for (int s = q; s < 7; s += 4)
            gload_lds16(w2 + (c * 7 + s) * 512 + lane * 8,
                        bB0 + (c & 1) * 7168 + s * 1024);
    };
    // -- A loads: 7 float4 per thread, row-contiguous (coalesced) --
    auto loadA = [&](f32x4* v, int c) {
        const f32x4* x4 = (const f32x4*)x;
        #pragma unroll
        for (int i = 0; i < 7; ++i) {
            const int g = i * 256 + tid;
            const int r = g / 28, c4 = g % 28;
            v[i] = x4[(size_t)(row0 + r) * 196 + c * 28 + c4];
        }
    };
    // -- A writes: f32x4 -> 4xf16 (8B) into fragment order, lane^s swizzle --
    auto writeA = [&](const f32x4* v, int c) {
        char* buf = bA0 + (c & 1) * 14336;
        #pragma unroll
        for (int i = 0; i < 7; ++i) {
            const int g = i * 256 + tid;
            const int r = g / 28, c4 = g % 28;
            const int s = c4 >> 2, b = (c4 >> 1) & 1;
            const int mt = r >> 5;
            const int ln = ((r & 31) + (b << 5)) ^ s;
            auto lo = __builtin_amdgcn_cvt_pkrtz(v[i].x, v[i].y); // __fp16x2
            auto hi = __builtin_amdgcn_cvt_pkrtz(v[i].z, v[i].w);
            uint2 d;
            d.x = __builtin_bit_cast(unsigned int, lo);
            d.y = __builtin_bit_cast(unsigned int, hi);
            *(uint2*)(buf + ((s * 2 + mt) * 64 + ln) * 16 + (c4 & 1) * 8) = d;
        }
    };
    // -- compute my ksteps of chunk c --
    auto compute = [&](int c) {
        char* bA = bA0 + (c & 1) * 14336;
        char* bB = bB0 + (c & 1) * 7168;
        const int sbeg = p ? 4 : 0, send = p ? 7 : 4;
        for (int s = sbeg; s < send; ++s) {
            f16x8 a = *(const f16x8*)(bA + ((s * 2 + m) * 64 + (lane ^ s)) * 16);
            f16x8 b = *(const f16x8*)(bB + s * 1024 + lane * 16);
            acc = __builtin_amdgcn_mfma_f32_32x32x16_f16(a, b, acc, 0, 0, 0);
        }
    };

    f32x4 v[7];
    loadA(v, 0); stageB(0); writeA(v, 0);
    for (int c = 0; c < 7; ++c) {
        __syncthreads();                         // publishes chunk c buffers
        if (c < 6) { loadA(v, c + 1); stageB(c + 1); }
        compute(c);
        if (c < 6) writeA(v, c + 1);
    }

    // -- pair-reduce K halves, square-sum Re/Im, store --
    __syncthreads();
    float* red = (float*)smem;                   // [2][64][17] = 8704 B
    if (p == 1) {
        #pragma unroll
        for (int i = 0; i < 16; ++i) red[(m * 64 + lane) * 17 + i] = acc[i];
    }
    __syncthreads();
    if (p == 0) {
        const int col = lane & 31;
        #pragma unroll
        for (int i = 0; i < 16; ++i) {
            const float sum = acc[i] + red[(m * 64 + lane) * 17 + i];
            const float sq = sum * sum;
            const float tot = sq + __shfl_xor(sq, 1, 64);
            if ((col & 1) == 0 && col < 20) {
                const int r = (i & 3) + 8 * (i >> 2) + 4 * (lane >> 5);
                out[(size_t)(row0 + m * 32 + r) * 10 + (col >> 1)] = tot;
            }
        }
    }
}

extern "C" void kernel_launch(void* const* d_in, const int* in_sizes, int n_in,
                              void* d_out, int out_size, void* d_ws, size_t ws_size,
                              hipStream_t stream) {
    const float* x     = (const float*)d_in[0];   // [32768,1,28,28] f32
    const float* phase = (const float*)d_in[1];   // [28,28] f32
    float* out = (float*)d_out;                   // [32768,10] f32
    _Float16* w2 = (_Float16*)d_ws;               // 49*512 f16 = 50 KB

    hipLaunchKernelGGL(prep_weights, dim3(1), dim3(SZ * SZ), 0, stream, phase, w2);

    const int B = in_sizes[0] / (SZ * SZ);        // 32768
    hipLaunchKernelGGL(focus_gemm, dim3(B / 64), dim3(256), 0, stream, x, w2, out);
}